// Round 5
// baseline (1158.688 us; speedup 1.0000x reference)
//
#include <hip/hip_runtime.h>
#include <hip/hip_bf16.h>
#include <cmath>

#define TT 512
#define BB 32
#define EE 256
#define HH 128
#define KCRF 12
#define NEGF (-10000.0f)

#define RL(v, l) __uint_as_float(__builtin_amdgcn_readlane(__float_as_uint(v), (l)))

// ---------------------------------------------------------------------------
// K1: XG[row=t*32+b][col 0..1023] = embed[sent[b,t]] . W_cat[col]^T + bias
// (unchanged)
// ---------------------------------------------------------------------------
__global__ __launch_bounds__(256) void k1_xg(const int* __restrict__ sent,
    const float* __restrict__ embed,
    const float* __restrict__ Wf, const float* __restrict__ bf,
    const float* __restrict__ Wr, const float* __restrict__ br,
    float* __restrict__ XG)
{
  __shared__ __align__(16) float As[64][36];
  __shared__ __align__(16) float Bs[128][36];
  const int tid = threadIdx.x;
  const int m0 = (blockIdx.x >> 3) * 64;
  const int n0 = (blockIdx.x & 7) * 128;
  const int ty = tid >> 4, tx = tid & 15;
  float acc[4][8];
#pragma unroll
  for (int i = 0; i < 4; ++i)
#pragma unroll
    for (int j = 0; j < 8; ++j) acc[i][j] = 0.f;

  for (int k0 = 0; k0 < 256; k0 += 32) {
#pragma unroll
    for (int r = 0; r < 2; ++r) {
      int idx = tid + r * 256;
      int row = idx >> 3;
      int c4 = (idx & 7) << 2;
      int R = m0 + row;
      int t = R >> 5, b = R & 31;
      const float4 v = *(const float4*)(embed + (long)sent[b * TT + t] * 256 + k0 + c4);
      *(float4*)&As[row][c4] = v;
    }
#pragma unroll
    for (int r = 0; r < 4; ++r) {
      int idx = tid + r * 256;
      int row = idx >> 3;
      int c4 = (idx & 7) << 2;
      int col = n0 + row;
      const float* src = (col < 512) ? (Wf + (long)col * 256) : (Wr + (long)(col - 512) * 256);
      const float4 v = *(const float4*)(src + k0 + c4);
      *(float4*)&Bs[row][c4] = v;
    }
    __syncthreads();
#pragma unroll
    for (int kk = 0; kk < 32; ++kk) {
      float a[4], bv[8];
#pragma unroll
      for (int i = 0; i < 4; ++i) a[i] = As[ty * 4 + i][kk];
#pragma unroll
      for (int j = 0; j < 8; ++j) bv[j] = Bs[tx + 16 * j][kk];
#pragma unroll
      for (int i = 0; i < 4; ++i)
#pragma unroll
        for (int j = 0; j < 8; ++j) acc[i][j] = fmaf(a[i], bv[j], acc[i][j]);
    }
    __syncthreads();
  }
#pragma unroll
  for (int i = 0; i < 4; ++i) {
    int R = m0 + ty * 4 + i;
#pragma unroll
    for (int j = 0; j < 8; ++j) {
      int col = n0 + tx + 16 * j;
      float bias = (col < 512) ? bf[col] : br[col - 512];
      XG[(long)R * 1024 + col] = acc[i][j] + bias;
    }
  }
}

// ---------------------------------------------------------------------------
// K2: LSTM scans. 64 WGs (one per dir,batch), 256 threads = 4 waves = 1
// wave/SIMD. Thread owns cols {tid, 256+tid} (so col1 is gate i/f -> sigmoid,
// col2 is g/o). h enters each wave via ONE distributed ds_read_b64 (lane l
// holds h[2l],h[2l+1]; 8B/lane, no broadcast bus cost), then a software-
// pipelined readlane stream puts h[k] in SGPRs; v_fmac v,s,v needs no LDS.
// This removes the 256KB/step LDS broadcast return traffic that capped
// rounds 1/3 at ~2250 cy/step.
// Gate layout: thread d<128 computes i[d],g[d] locally; f[d],o[d] come from
// thread 128+d via a 256-float LDS exchange.
// ---------------------------------------------------------------------------
__global__ __launch_bounds__(256, 1)
void k2_scan(const float* __restrict__ XG,
    const float* __restrict__ Whf, const float* __restrict__ Whr,
    const float* __restrict__ h0, const float* __restrict__ c0,
    float* __restrict__ HS)
{
  const int wg = blockIdx.x;
  const int dir = wg >> 5;
  const int b = wg & 31;
  const int tid = threadIdx.x;
  const int lane = tid & 63;
  const float* Wh = dir ? Whr : Whf;

  // weights for col1 = tid and col2 = 256+tid (128 floats each)
  float w1[128], w2[128];
#pragma unroll
  for (int i = 0; i < 32; ++i) {
    float4 v = *(const float4*)(Wh + (long)tid * 128 + 4 * i);
    w1[4 * i] = v.x; w1[4 * i + 1] = v.y; w1[4 * i + 2] = v.z; w1[4 * i + 3] = v.w;
  }
#pragma unroll
  for (int i = 0; i < 32; ++i) {
    float4 v = *(const float4*)(Wh + (long)(256 + tid) * 128 + 4 * i);
    w2[4 * i] = v.x; w2[4 * i + 1] = v.y; w2[4 * i + 2] = v.z; w2[4 * i + 3] = v.w;
  }

  __shared__ __align__(16) float hs[128];
  __shared__ float gsf[128];   // f-gate activations from upper threads
  __shared__ float gso[128];   // o-gate activations from upper threads
  float c = 0.f;
  if (tid < 128) {
    hs[tid] = h0[(dir * 32 + b) * 128 + tid];
    c = c0[(dir * 32 + b) * 128 + tid];
  }
  __syncthreads();

  const int t0 = dir ? (TT - 1) : 0;
  const long stepoff = dir ? -32768 : 32768;     // 32*1024 floats per t
  const float* xp = XG + ((long)t0 * 32 + b) * 1024 + dir * 512 + tid;
  float xg1 = xp[0], xg2 = xp[256];
  const bool lower = (tid < 128);                // wave-uniform

  for (int s = 0; s < TT; ++s) {
    const int t = dir ? (TT - 1 - s) : s;
    float nx1 = 0.f, nx2 = 0.f;
    if (s + 1 < TT) { xp += stepoff; nx1 = xp[0]; nx2 = xp[256]; }

    // distributed h: lane l holds h[2l], h[2l+1]
    const float2 hp = *(const float2*)(hs + 2 * lane);

    float a1 = xg1, b1 = 0.f, a2 = xg2, b2 = 0.f;
    float sA[8], sB[8];
    // software-pipelined readlane -> SGPR blocks (8 h values per block)
#define RLB(dst, blk) \
    { dst[0] = RL(hp.x, (blk) * 4 + 0); dst[1] = RL(hp.y, (blk) * 4 + 0); \
      dst[2] = RL(hp.x, (blk) * 4 + 1); dst[3] = RL(hp.y, (blk) * 4 + 1); \
      dst[4] = RL(hp.x, (blk) * 4 + 2); dst[5] = RL(hp.y, (blk) * 4 + 2); \
      dst[6] = RL(hp.x, (blk) * 4 + 3); dst[7] = RL(hp.y, (blk) * 4 + 3); }
#define FMAB(src, blk) \
    { a1 = fmaf(w1[(blk) * 8 + 0], src[0], a1); a2 = fmaf(w2[(blk) * 8 + 0], src[0], a2); \
      b1 = fmaf(w1[(blk) * 8 + 1], src[1], b1); b2 = fmaf(w2[(blk) * 8 + 1], src[1], b2); \
      a1 = fmaf(w1[(blk) * 8 + 2], src[2], a1); a2 = fmaf(w2[(blk) * 8 + 2], src[2], a2); \
      b1 = fmaf(w1[(blk) * 8 + 3], src[3], b1); b2 = fmaf(w2[(blk) * 8 + 3], src[3], b2); \
      a1 = fmaf(w1[(blk) * 8 + 4], src[4], a1); a2 = fmaf(w2[(blk) * 8 + 4], src[4], a2); \
      b1 = fmaf(w1[(blk) * 8 + 5], src[5], b1); b2 = fmaf(w2[(blk) * 8 + 5], src[5], b2); \
      a1 = fmaf(w1[(blk) * 8 + 6], src[6], a1); a2 = fmaf(w2[(blk) * 8 + 6], src[6], a2); \
      b1 = fmaf(w1[(blk) * 8 + 7], src[7], b1); b2 = fmaf(w2[(blk) * 8 + 7], src[7], b2); }

    RLB(sA, 0);
    RLB(sB, 1);  FMAB(sA, 0);
    RLB(sA, 2);  FMAB(sB, 1);
    RLB(sB, 3);  FMAB(sA, 2);
    RLB(sA, 4);  FMAB(sB, 3);
    RLB(sB, 5);  FMAB(sA, 4);
    RLB(sA, 6);  FMAB(sB, 5);
    RLB(sB, 7);  FMAB(sA, 6);
    RLB(sA, 8);  FMAB(sB, 7);
    RLB(sB, 9);  FMAB(sA, 8);
    RLB(sA, 10); FMAB(sB, 9);
    RLB(sB, 11); FMAB(sA, 10);
    RLB(sA, 12); FMAB(sB, 11);
    RLB(sB, 13); FMAB(sA, 12);
    RLB(sA, 14); FMAB(sB, 13);
    RLB(sB, 15); FMAB(sA, 14);
    FMAB(sB, 15);
#undef RLB
#undef FMAB

    const float g1 = a1 + b1;       // col1 pre-activation (i or f)
    const float g2 = a2 + b2;       // col2 pre-activation (g or o)
    const float act1 = 1.f / (1.f + expf(-g1));             // sigmoid (i/f)
    const float act2 = lower ? tanhf(g2)                    // g
                             : (1.f / (1.f + expf(-g2)));   // o
    if (!lower) { gsf[tid - 128] = act1; gso[tid - 128] = act2; }
    __syncthreads();                 // f,o published; all hp reads done
    if (lower) {
      const float ig = act1, gg = act2;
      const float fg = gsf[tid], og = gso[tid];
      c = fmaf(fg, c, ig * gg);
      const float h = og * tanhf(c);
      hs[tid] = h;
      HS[((long)t * 32 + b) * 256 + dir * 128 + tid] = h;
    }
    __syncthreads();                 // hs ready for next step
    xg1 = nx1; xg2 = nx2;
  }
}

// ---------------------------------------------------------------------------
// K3: feats. FE layout [t][k][b]. (unchanged)
// ---------------------------------------------------------------------------
__global__ __launch_bounds__(64) void k3_feats(const float* __restrict__ HS,
    const float* __restrict__ Wout, const float* __restrict__ bout,
    float* __restrict__ FE)
{
  __shared__ __align__(16) float ws[12 * 256];
  __shared__ float bs[12];
  const int tid = threadIdx.x;
  for (int i = tid; i < 768; i += 64)
    ((float4*)ws)[i] = ((const float4*)Wout)[i];
  if (tid < 12) bs[tid] = bout[tid];
  __syncthreads();
  const long row = (long)blockIdx.x * 64 + tid;
  const float4* hp = (const float4*)(HS + row * 256);
  float acc[12];
#pragma unroll
  for (int k = 0; k < 12; ++k) acc[k] = bs[k];
  for (int e4 = 0; e4 < 64; ++e4) {
    float4 hv = hp[e4];
#pragma unroll
    for (int k = 0; k < 12; ++k) {
      const float4 wv = *(const float4*)&ws[k * 256 + e4 * 4];
      acc[k] = fmaf(hv.x, wv.x, acc[k]);
      acc[k] = fmaf(hv.y, wv.y, acc[k]);
      acc[k] = fmaf(hv.z, wv.z, acc[k]);
      acc[k] = fmaf(hv.w, wv.w, acc[k]);
    }
  }
  const int t = (int)(row >> 5), b = (int)(row & 31);
#pragma unroll
  for (int k = 0; k < 12; ++k) FE[((long)t * 12 + k) * 32 + b] = acc[k];
}

// ---------------------------------------------------------------------------
// K4: Viterbi, double-buffered scores (1 barrier/step), nibble-packed
// pointers in LDS for the backtrace. (unchanged)
// ---------------------------------------------------------------------------
__global__ __launch_bounds__(384) void k4_viterbi(const float* __restrict__ FE,
    const float* __restrict__ trans, int* __restrict__ out)
{
  __shared__ unsigned char nib[TT * 192];   // 98304 B
  __shared__ float sc[2][32][12];
  __shared__ float tr[144];
  __shared__ unsigned char stag[2][384];
  __shared__ int btag[32];
  const int tid = threadIdx.x;
  const int b = tid & 31, nxt = tid >> 5;
  if (tid < 144) tr[tid] = trans[tid];
  if (nxt == 0) {
#pragma unroll
    for (int p = 0; p < 12; ++p) sc[0][b][p] = (p == 9) ? 0.f : NEGF;  // START=9
  }
  __syncthreads();
  float fnext = FE[nxt * 32 + b];
  for (int t = 0; t < TT; ++t) {
    const int cur = t & 1;
    const float feat = fnext;
    if (t + 1 < TT) fnext = FE[(t + 1) * 384 + nxt * 32 + b];
    float best = -1e30f; int arg = 0;
#pragma unroll
    for (int p = 0; p < 12; ++p) {
      float v = sc[cur][b][p] + tr[nxt * 12 + p];
      if (v > best) { best = v; arg = p; }
    }
    sc[cur ^ 1][b][nxt] = best + feat;
    stag[cur][b * 12 + nxt] = (unsigned char)arg;
    if (t > 0 && tid < 192) {
      const int bb = tid / 6, p = tid % 6;
      nib[(t - 1) * 192 + tid] =
          (unsigned char)(stag[cur ^ 1][bb * 12 + 2 * p] |
                          (stag[cur ^ 1][bb * 12 + 2 * p + 1] << 4));
    }
    __syncthreads();
  }
  if (tid < 192) {
    const int bb = tid / 6, p = tid % 6;
    nib[511 * 192 + tid] =
        (unsigned char)(stag[1][bb * 12 + 2 * p] | (stag[1][bb * 12 + 2 * p + 1] << 4));
  }
  if (nxt == 0) {
    float best = -1e30f; int arg = 0;
#pragma unroll
    for (int p = 0; p < 12; ++p) {
      float v = sc[0][b][p] + tr[10 * 12 + p];   // STOP=10
      if (v > best) { best = v; arg = p; }
    }
    btag[b] = arg;
  }
  __syncthreads();
  if (tid < 32) {
    int tag = btag[b];
    for (int t = TT - 1; t >= 0; --t) {
      out[b * TT + t] = tag;
      if (t) {
        unsigned char v = nib[t * 192 + b * 6 + (tag >> 1)];
        tag = (tag & 1) ? (v >> 4) : (v & 15);
      }
    }
  }
}

// ---------------------------------------------------------------------------
extern "C" void kernel_launch(void* const* d_in, const int* in_sizes, int n_in,
                              void* d_out, int out_size, void* d_ws, size_t ws_size,
                              hipStream_t stream)
{
  const int* sent = (const int*)d_in[0];
  const float* h0 = (const float*)d_in[1];
  const float* c0 = (const float*)d_in[2];
  const float* embed = (const float*)d_in[3];
  const float* Wif = (const float*)d_in[4];
  const float* Whf = (const float*)d_in[5];
  const float* bf = (const float*)d_in[6];
  const float* Wir = (const float*)d_in[7];
  const float* Whr = (const float*)d_in[8];
  const float* br = (const float*)d_in[9];
  const float* Wout = (const float*)d_in[10];
  const float* bout = (const float*)d_in[11];
  const float* trans = (const float*)d_in[12];

  char* ws = (char*)d_ws;
  float* XG = (float*)ws;                                   // 67,108,864 B
  float* HS = (float*)(ws + 67108864);                      // 16,777,216 B
  float* FE = (float*)(ws + 67108864 + 16777216);           //    786,432 B
  int* out = (int*)d_out;

  hipLaunchKernelGGL(k1_xg, dim3(2048), dim3(256), 0, stream,
                     sent, embed, Wif, bf, Wir, br, XG);
  hipLaunchKernelGGL(k2_scan, dim3(64), dim3(256), 0, stream,
                     XG, Whf, Whr, h0, c0, HS);
  hipLaunchKernelGGL(k3_feats, dim3(256), dim3(64), 0, stream,
                     HS, Wout, bout, FE);
  hipLaunchKernelGGL(k4_viterbi, dim3(1), dim3(384), 0, stream,
                     FE, trans, out);
}

// Round 6
// 976.138 us; speedup vs baseline: 1.1870x; 1.1870x over previous
//
#include <hip/hip_runtime.h>
#include <hip/hip_bf16.h>
#include <cmath>

#define TT 512
#define BB 32
#define EE 256
#define HH 128
#define KCRF 12
#define NEGF (-10000.0f)

// ---------------------------------------------------------------------------
// K1: XG[row=t*32+b][col 0..1023] = embed[sent[b,t]] . W_cat[col]^T + bias
// (unchanged)
// ---------------------------------------------------------------------------
__global__ __launch_bounds__(256) void k1_xg(const int* __restrict__ sent,
    const float* __restrict__ embed,
    const float* __restrict__ Wf, const float* __restrict__ bf,
    const float* __restrict__ Wr, const float* __restrict__ br,
    float* __restrict__ XG)
{
  __shared__ __align__(16) float As[64][36];
  __shared__ __align__(16) float Bs[128][36];
  const int tid = threadIdx.x;
  const int m0 = (blockIdx.x >> 3) * 64;
  const int n0 = (blockIdx.x & 7) * 128;
  const int ty = tid >> 4, tx = tid & 15;
  float acc[4][8];
#pragma unroll
  for (int i = 0; i < 4; ++i)
#pragma unroll
    for (int j = 0; j < 8; ++j) acc[i][j] = 0.f;

  for (int k0 = 0; k0 < 256; k0 += 32) {
#pragma unroll
    for (int r = 0; r < 2; ++r) {
      int idx = tid + r * 256;
      int row = idx >> 3;
      int c4 = (idx & 7) << 2;
      int R = m0 + row;
      int t = R >> 5, b = R & 31;
      const float4 v = *(const float4*)(embed + (long)sent[b * TT + t] * 256 + k0 + c4);
      *(float4*)&As[row][c4] = v;
    }
#pragma unroll
    for (int r = 0; r < 4; ++r) {
      int idx = tid + r * 256;
      int row = idx >> 3;
      int c4 = (idx & 7) << 2;
      int col = n0 + row;
      const float* src = (col < 512) ? (Wf + (long)col * 256) : (Wr + (long)(col - 512) * 256);
      const float4 v = *(const float4*)(src + k0 + c4);
      *(float4*)&Bs[row][c4] = v;
    }
    __syncthreads();
#pragma unroll
    for (int kk = 0; kk < 32; ++kk) {
      float a[4], bv[8];
#pragma unroll
      for (int i = 0; i < 4; ++i) a[i] = As[ty * 4 + i][kk];
#pragma unroll
      for (int j = 0; j < 8; ++j) bv[j] = Bs[tx + 16 * j][kk];
#pragma unroll
      for (int i = 0; i < 4; ++i)
#pragma unroll
        for (int j = 0; j < 8; ++j) acc[i][j] = fmaf(a[i], bv[j], acc[i][j]);
    }
    __syncthreads();
  }
#pragma unroll
  for (int i = 0; i < 4; ++i) {
    int R = m0 + ty * 4 + i;
#pragma unroll
    for (int j = 0; j < 8; ++j) {
      int col = n0 + tx + 16 * j;
      float bias = (col < 512) ? bf[col] : br[col - 512];
      XG[(long)R * 1024 + col] = acc[i][j] + bias;
    }
  }
}

// ---------------------------------------------------------------------------
// K2: LSTM scans. 64 WGs (one per dir,batch chain), 256 threads = 4 waves =
// 1 wave/SIMD. Thread owns cols {tid, tid+256}; h enters via wave-uniform
// ds_read_b128 broadcast (the R1/R3 proven path). Key sizing insight from
// rounds 1-5: broadcast LDS return traffic scales with WAVE COUNT (each
// wave-wide read delivers 64 lanes x 16B at ~128B/cy even for uniform
// addresses), so 4 waves x 2 cols/thread halves R1/R3's 2048cy/step LDS cost
// to 1024cy while per-SIMD VALU stays ~1064cy (1 wave/SIMD). Readlane
// variants (R2/R5) are falsified: SGPR RAW hazards can't be hidden at low
// occupancy. Gate exchange layout identical to R5 (correctness-proven).
// ---------------------------------------------------------------------------
__global__ __launch_bounds__(256, 1)
void k2_scan(const float* __restrict__ XG,
    const float* __restrict__ Whf, const float* __restrict__ Whr,
    const float* __restrict__ h0, const float* __restrict__ c0,
    float* __restrict__ HS)
{
  const int wg = blockIdx.x;
  const int dir = wg >> 5;
  const int b = wg & 31;
  const int tid = threadIdx.x;
  const float* Wh = dir ? Whr : Whf;

  // weights for col1 = tid (gate i/f) and col2 = tid+256 (gate g/o)
  float4 w1[32], w2[32];
#pragma unroll
  for (int i = 0; i < 32; ++i)
    w1[i] = *(const float4*)(Wh + (long)tid * 128 + 4 * i);
#pragma unroll
  for (int i = 0; i < 32; ++i)
    w2[i] = *(const float4*)(Wh + (long)(256 + tid) * 128 + 4 * i);

  __shared__ __align__(16) float hs[128];
  __shared__ float gsf[128];   // f-gate activations from upper threads
  __shared__ float gso[128];   // o-gate activations from upper threads
  float c = 0.f;
  if (tid < 128) {
    hs[tid] = h0[(dir * 32 + b) * 128 + tid];
    c = c0[(dir * 32 + b) * 128 + tid];
  }
  __syncthreads();

  const int t0 = dir ? (TT - 1) : 0;
  const long stepoff = dir ? -32768 : 32768;     // 32*1024 floats per t
  const float* xp = XG + ((long)t0 * 32 + b) * 1024 + dir * 512 + tid;
  float xg1 = xp[0], xg2 = xp[256];
  const bool lower = (tid < 128);                // wave-uniform

  for (int s = 0; s < TT; ++s) {
    const int t = dir ? (TT - 1 - s) : s;
    float nx1 = 0.f, nx2 = 0.f;
    if (s + 1 < TT) { xp += stepoff; nx1 = xp[0]; nx2 = xp[256]; }

    float a1 = xg1, b1 = 0.f, a2 = xg2, b2 = 0.f;
#pragma unroll
    for (int i = 0; i < 32; ++i) {
      const float4 hv = *(const float4*)(hs + 4 * i);   // uniform -> broadcast
      a1 = fmaf(w1[i].x, hv.x, a1);
      b1 = fmaf(w1[i].y, hv.y, b1);
      a1 = fmaf(w1[i].z, hv.z, a1);
      b1 = fmaf(w1[i].w, hv.w, b1);
      a2 = fmaf(w2[i].x, hv.x, a2);
      b2 = fmaf(w2[i].y, hv.y, b2);
      a2 = fmaf(w2[i].z, hv.z, a2);
      b2 = fmaf(w2[i].w, hv.w, b2);
    }
    const float g1 = a1 + b1;       // col1 pre-activation (i or f)
    const float g2 = a2 + b2;       // col2 pre-activation (g or o)
    const float act1 = 1.f / (1.f + expf(-g1));             // sigmoid (i/f)
    const float act2 = lower ? tanhf(g2)                    // g
                             : (1.f / (1.f + expf(-g2)));   // o
    if (!lower) { gsf[tid - 128] = act1; gso[tid - 128] = act2; }
    __syncthreads();                 // f,o published; all hs reads done
    if (lower) {
      const float ig = act1, gg = act2;
      const float fg = gsf[tid], og = gso[tid];
      c = fmaf(fg, c, ig * gg);
      const float h = og * tanhf(c);
      hs[tid] = h;
      HS[((long)t * 32 + b) * 256 + dir * 128 + tid] = h;
    }
    __syncthreads();                 // hs ready for next step
    xg1 = nx1; xg2 = nx2;
  }
}

// ---------------------------------------------------------------------------
// K3: feats. FE layout [t][k][b]. (unchanged)
// ---------------------------------------------------------------------------
__global__ __launch_bounds__(64) void k3_feats(const float* __restrict__ HS,
    const float* __restrict__ Wout, const float* __restrict__ bout,
    float* __restrict__ FE)
{
  __shared__ __align__(16) float ws[12 * 256];
  __shared__ float bs[12];
  const int tid = threadIdx.x;
  for (int i = tid; i < 768; i += 64)
    ((float4*)ws)[i] = ((const float4*)Wout)[i];
  if (tid < 12) bs[tid] = bout[tid];
  __syncthreads();
  const long row = (long)blockIdx.x * 64 + tid;
  const float4* hp = (const float4*)(HS + row * 256);
  float acc[12];
#pragma unroll
  for (int k = 0; k < 12; ++k) acc[k] = bs[k];
  for (int e4 = 0; e4 < 64; ++e4) {
    float4 hv = hp[e4];
#pragma unroll
    for (int k = 0; k < 12; ++k) {
      const float4 wv = *(const float4*)&ws[k * 256 + e4 * 4];
      acc[k] = fmaf(hv.x, wv.x, acc[k]);
      acc[k] = fmaf(hv.y, wv.y, acc[k]);
      acc[k] = fmaf(hv.z, wv.z, acc[k]);
      acc[k] = fmaf(hv.w, wv.w, acc[k]);
    }
  }
  const int t = (int)(row >> 5), b = (int)(row & 31);
#pragma unroll
  for (int k = 0; k < 12; ++k) FE[((long)t * 12 + k) * 32 + b] = acc[k];
}

// ---------------------------------------------------------------------------
// K4: Viterbi, double-buffered scores (1 barrier/step), nibble-packed
// pointers in LDS for the backtrace. (unchanged)
// ---------------------------------------------------------------------------
__global__ __launch_bounds__(384) void k4_viterbi(const float* __restrict__ FE,
    const float* __restrict__ trans, int* __restrict__ out)
{
  __shared__ unsigned char nib[TT * 192];   // 98304 B
  __shared__ float sc[2][32][12];
  __shared__ float tr[144];
  __shared__ unsigned char stag[2][384];
  __shared__ int btag[32];
  const int tid = threadIdx.x;
  const int b = tid & 31, nxt = tid >> 5;
  if (tid < 144) tr[tid] = trans[tid];
  if (nxt == 0) {
#pragma unroll
    for (int p = 0; p < 12; ++p) sc[0][b][p] = (p == 9) ? 0.f : NEGF;  // START=9
  }
  __syncthreads();
  float fnext = FE[nxt * 32 + b];
  for (int t = 0; t < TT; ++t) {
    const int cur = t & 1;
    const float feat = fnext;
    if (t + 1 < TT) fnext = FE[(t + 1) * 384 + nxt * 32 + b];
    float best = -1e30f; int arg = 0;
#pragma unroll
    for (int p = 0; p < 12; ++p) {
      float v = sc[cur][b][p] + tr[nxt * 12 + p];
      if (v > best) { best = v; arg = p; }
    }
    sc[cur ^ 1][b][nxt] = best + feat;
    stag[cur][b * 12 + nxt] = (unsigned char)arg;
    if (t > 0 && tid < 192) {
      const int bb = tid / 6, p = tid % 6;
      nib[(t - 1) * 192 + tid] =
          (unsigned char)(stag[cur ^ 1][bb * 12 + 2 * p] |
                          (stag[cur ^ 1][bb * 12 + 2 * p + 1] << 4));
    }
    __syncthreads();
  }
  if (tid < 192) {
    const int bb = tid / 6, p = tid % 6;
    nib[511 * 192 + tid] =
        (unsigned char)(stag[1][bb * 12 + 2 * p] | (stag[1][bb * 12 + 2 * p + 1] << 4));
  }
  if (nxt == 0) {
    float best = -1e30f; int arg = 0;
#pragma unroll
    for (int p = 0; p < 12; ++p) {
      float v = sc[0][b][p] + tr[10 * 12 + p];   // STOP=10
      if (v > best) { best = v; arg = p; }
    }
    btag[b] = arg;
  }
  __syncthreads();
  if (tid < 32) {
    int tag = btag[b];
    for (int t = TT - 1; t >= 0; --t) {
      out[b * TT + t] = tag;
      if (t) {
        unsigned char v = nib[t * 192 + b * 6 + (tag >> 1)];
        tag = (tag & 1) ? (v >> 4) : (v & 15);
      }
    }
  }
}

// ---------------------------------------------------------------------------
extern "C" void kernel_launch(void* const* d_in, const int* in_sizes, int n_in,
                              void* d_out, int out_size, void* d_ws, size_t ws_size,
                              hipStream_t stream)
{
  const int* sent = (const int*)d_in[0];
  const float* h0 = (const float*)d_in[1];
  const float* c0 = (const float*)d_in[2];
  const float* embed = (const float*)d_in[3];
  const float* Wif = (const float*)d_in[4];
  const float* Whf = (const float*)d_in[5];
  const float* bf = (const float*)d_in[6];
  const float* Wir = (const float*)d_in[7];
  const float* Whr = (const float*)d_in[8];
  const float* br = (const float*)d_in[9];
  const float* Wout = (const float*)d_in[10];
  const float* bout = (const float*)d_in[11];
  const float* trans = (const float*)d_in[12];

  char* ws = (char*)d_ws;
  float* XG = (float*)ws;                                   // 67,108,864 B
  float* HS = (float*)(ws + 67108864);                      // 16,777,216 B
  float* FE = (float*)(ws + 67108864 + 16777216);           //    786,432 B
  int* out = (int*)d_out;

  hipLaunchKernelGGL(k1_xg, dim3(2048), dim3(256), 0, stream,
                     sent, embed, Wif, bf, Wir, br, XG);
  hipLaunchKernelGGL(k2_scan, dim3(64), dim3(256), 0, stream,
                     XG, Whf, Whr, h0, c0, HS);
  hipLaunchKernelGGL(k3_feats, dim3(256), dim3(64), 0, stream,
                     HS, Wout, bout, FE);
  hipLaunchKernelGGL(k4_viterbi, dim3(1), dim3(384), 0, stream,
                     FE, trans, out);
}